// Round 6
// baseline (622.557 us; speedup 1.0000x reference)
//
#include <hip/hip_runtime.h>

#define UNITS 64
#define NNODES 50000
#define NBUCK 512          // bucket = row*512/50000, 97-98 rows each
#define CAP 3584           // records per bucket region (mean 3125, sigma ~56 -> +8 sigma)
#define BIN_TPB 1024
#define BIN_EPT 8          // 8192 edges per bin block
#define MAXROWS 98
#define SPMM_TPB 512

typedef unsigned long long u64;
typedef unsigned int u32;
typedef unsigned short u16;

// ---------------- workspace layout (bytes) ----------------
// kb      : [0,        6400000)   3.2M bf16 (kernel cast)
// gcursor : [6400000,  6402048)   512 ints
// edges   : [6402048,  6402048 + NBUCK*CAP*8 = 14.68MB)  packed records:
//           bits[63:32]=value(f32), [31:23]=bucket, [22:16]=row-in-bucket, [15:0]=col

__device__ __forceinline__ int rowbase_of(u32 b) {
    return (int)((b * 50000u + 511u) >> 9);   // ceil(b*50000/512)
}

// f32 -> bf16 (RN) convert, fused with gcursor init
__global__ void gc_prep(const float* __restrict__ kf, u16* __restrict__ kb,
                        int* __restrict__ gcursor, int n4) {
    int i = blockIdx.x * blockDim.x + threadIdx.x;
    if (blockIdx.x == 0 && threadIdx.x < 256) {
        gcursor[threadIdx.x]       = threadIdx.x * CAP;
        gcursor[threadIdx.x + 256] = (threadIdx.x + 256) * CAP;
    }
    if (i >= n4) return;
    float4 f = ((const float4*)kf)[i];
    ushort4 o;
    u32 b;
    b = __float_as_uint(f.x); o.x = (u16)((b + 0x7FFFu + ((b >> 16) & 1u)) >> 16);
    b = __float_as_uint(f.y); o.y = (u16)((b + 0x7FFFu + ((b >> 16) & 1u)) >> 16);
    b = __float_as_uint(f.z); o.z = (u16)((b + 0x7FFFu + ((b >> 16) & 1u)) >> 16);
    b = __float_as_uint(f.w); o.w = (u16)((b + 0x7FFFu + ((b >> 16) & 1u)) >> 16);
    ((ushort4*)kb)[i] = o;
}

// Bin edges into padded per-bucket regions with COALESCED writes:
// rank via LDS hist, scatter to LDS stage at local sorted position, then
// stream stage out (consecutive threads -> consecutive global addresses).
__global__ __launch_bounds__(BIN_TPB) void gc_bin(const int* __restrict__ rows,
                                                  const int* __restrict__ cols,
                                                  const float* __restrict__ values,
                                                  int* __restrict__ gcursor,
                                                  u64* __restrict__ edges, int nnz) {
    __shared__ u64 stage[BIN_TPB * BIN_EPT];   // 64 KB
    __shared__ int hist[NBUCK];                // 2 KB
    __shared__ int lstart[NBUCK];              // 2 KB
    __shared__ int delta[NBUCK];               // 2 KB
    int t = threadIdx.x;
    if (t < NBUCK) hist[t] = 0;
    __syncthreads();

    int blockStart = blockIdx.x * (BIN_TPB * BIN_EPT);
    int cnt = min(BIN_TPB * BIN_EPT, nnz - blockStart);

    u64 rec[BIN_EPT];
    int bk[BIN_EPT];
    int rk[BIN_EPT];
#pragma unroll
    for (int k = 0; k < BIN_EPT; ++k) {
        int idx = blockStart + k * BIN_TPB + t;
        if (idx < nnz) {
            int r = rows[idx];
            u32 c = (u32)cols[idx];
            u32 v = __float_as_uint(values[idx]);
            int b = (int)(((u32)r * 512u) / 50000u);
            int lrow = r - rowbase_of((u32)b);
            rec[k] = ((u64)v << 32) | ((u64)(u32)b << 23) | ((u64)(u32)lrow << 16) | (u64)c;
            bk[k] = b;
            rk[k] = atomicAdd(&hist[b], 1);
        } else {
            bk[k] = -1;
        }
    }
    __syncthreads();

    // exclusive scan of hist -> lstart; grab global cursor base; delta = gbase - lstart
    int v0 = (t < NBUCK) ? hist[t] : 0;
    if (t < NBUCK) lstart[t] = v0;
    __syncthreads();
    for (int off = 1; off < NBUCK; off <<= 1) {
        int x = 0;
        if (t < NBUCK && t >= off) x = lstart[t - off];
        __syncthreads();
        if (t < NBUCK) lstart[t] += x;
        __syncthreads();
    }
    if (t < NBUCK) {
        int excl = lstart[t] - v0;
        int gbase = (v0 > 0) ? atomicAdd(&gcursor[t], v0) : 0;
        delta[t] = gbase - excl;
        lstart[t] = excl;
    }
    __syncthreads();

#pragma unroll
    for (int k = 0; k < BIN_EPT; ++k) {
        if (bk[k] >= 0) stage[lstart[bk[k]] + rk[k]] = rec[k];
    }
    __syncthreads();

    for (int i = t; i < cnt; i += BIN_TPB) {
        u64 r = stage[i];
        int b = (int)((r >> 23) & 0x1FF);
        edges[delta[b] + i] = r;   // coalesced within bucket runs
    }
}

// One block per bucket: accumulate directly into LDS f32 out-tile via ds_add_f32.
// Wave per edge-chunk, lane = unit; bf16 kernel gather; fused bias+relu store.
__global__ __launch_bounds__(SPMM_TPB) void gc_spmm(const u64* __restrict__ edges,
                                                    const int* __restrict__ gcursor,
                                                    const u16* __restrict__ kb,
                                                    const float* __restrict__ bias,
                                                    float* __restrict__ out) {
    __shared__ float tile[MAXROWS * UNITS];   // 25 KB
    int b = blockIdx.x;
    int t = threadIdx.x;
    int rowlo = rowbase_of((u32)b);
    int nrows = rowbase_of((u32)b + 1u) - rowlo;
    int count = gcursor[b] - b * CAP;
    const u64* eb = edges + (size_t)b * CAP;

    int total = nrows * UNITS;
    for (int i = t; i < total; i += SPMM_TPB) tile[i] = 0.0f;
    __syncthreads();

    int lane = t & 63;
    int w = t >> 6;                       // 8 waves
    int chunk = (count + 7) >> 3;
    int j = w * chunk;
    int jhi = min(j + chunk, count);

    for (; j + 4 <= jhi; j += 4) {
        u64 r0 = eb[j + 0], r1 = eb[j + 1], r2 = eb[j + 2], r3 = eb[j + 3];
        float k0 = __uint_as_float((u32)kb[((u32)r0 & 0xFFFFu) * UNITS + lane] << 16);
        float k1 = __uint_as_float((u32)kb[((u32)r1 & 0xFFFFu) * UNITS + lane] << 16);
        float k2 = __uint_as_float((u32)kb[((u32)r2 & 0xFFFFu) * UNITS + lane] << 16);
        float k3 = __uint_as_float((u32)kb[((u32)r3 & 0xFFFFu) * UNITS + lane] << 16);
        atomicAdd(&tile[(int)((r0 >> 16) & 0x7F) * UNITS + lane], __uint_as_float((u32)(r0 >> 32)) * k0);
        atomicAdd(&tile[(int)((r1 >> 16) & 0x7F) * UNITS + lane], __uint_as_float((u32)(r1 >> 32)) * k1);
        atomicAdd(&tile[(int)((r2 >> 16) & 0x7F) * UNITS + lane], __uint_as_float((u32)(r2 >> 32)) * k2);
        atomicAdd(&tile[(int)((r3 >> 16) & 0x7F) * UNITS + lane], __uint_as_float((u32)(r3 >> 32)) * k3);
    }
    for (; j < jhi; ++j) {
        u64 r = eb[j];
        float k = __uint_as_float((u32)kb[((u32)r & 0xFFFFu) * UNITS + lane] << 16);
        atomicAdd(&tile[(int)((r >> 16) & 0x7F) * UNITS + lane], __uint_as_float((u32)(r >> 32)) * k);
    }
    __syncthreads();

    float bl = bias[t & 63];  // stride 512 is a multiple of 64 -> (i&63) constant
    for (int i = t; i < total; i += SPMM_TPB) {
        out[(size_t)rowlo * UNITS + i] = fmaxf(tile[i] + bl, 0.0f);
    }
}

extern "C" void kernel_launch(void* const* d_in, const int* in_sizes, int n_in,
                              void* d_out, int out_size, void* d_ws, size_t ws_size,
                              hipStream_t stream) {
    const int*   rows   = (const int*)d_in[0];
    const int*   cols   = (const int*)d_in[1];
    const float* values = (const float*)d_in[2];
    const float* kern   = (const float*)d_in[3];
    const float* bias   = (const float*)d_in[4];
    float* out = (float*)d_out;

    const int nnz = in_sizes[0];

    char* ws = (char*)d_ws;
    u16* kb      = (u16*)(ws + 0);
    int* gcursor = (int*)(ws + 6400000);
    u64* edges   = (u64*)(ws + 6402048);

    int n4 = (NNODES * UNITS) / 4;  // 800000
    gc_prep<<<(n4 + 255) / 256, 256, 0, stream>>>(kern, kb, gcursor, n4);

    gc_bin<<<(nnz + BIN_TPB * BIN_EPT - 1) / (BIN_TPB * BIN_EPT), BIN_TPB, 0, stream>>>(
        rows, cols, values, gcursor, edges, nnz);

    gc_spmm<<<NBUCK, SPMM_TPB, 0, stream>>>(edges, gcursor, kb, bias, out);
}

// Round 7
// 135.092 us; speedup vs baseline: 4.6084x; 4.6084x over previous
//
#include <hip/hip_runtime.h>

#define UNITS 64
#define NNODES 50000
#define NBUCK 512          // bucket = row*512/50000, 97-98 rows each
#define CAP 3584           // records per bucket region (mean 3125, sigma ~56 -> +8 sigma)
#define BIN_TPB 512
#define BIN_EPT 8          // 4096 edges per bin block -> 391 blocks
#define SPMM_TPB 1024

typedef unsigned long long u64;
typedef unsigned int u32;
typedef unsigned short u16;

// ---------------- workspace layout (bytes) ----------------
// kb      : [0,        6400000)   3.2M bf16 (kernel cast)
// gcursor : [6400000,  6402048)   512 ints
// edges   : [6402048,  6402048 + NBUCK*CAP*8 = 14.68MB)  packed records:
//           bits[63:32]=value(f32), [31:23]=bucket, [22:16]=row-in-bucket, [15:0]=col

__device__ __forceinline__ int rowbase_of(u32 b) {
    return (int)((b * 50000u + 511u) >> 9);   // ceil(b*50000/512)
}

// f32 -> bf16 (RN) convert, fused with gcursor init
__global__ void gc_prep(const float* __restrict__ kf, u16* __restrict__ kb,
                        int* __restrict__ gcursor, int n4) {
    int i = blockIdx.x * blockDim.x + threadIdx.x;
    if (blockIdx.x == 0 && threadIdx.x < 256) {
        gcursor[threadIdx.x]       = threadIdx.x * CAP;
        gcursor[threadIdx.x + 256] = (threadIdx.x + 256) * CAP;
    }
    if (i >= n4) return;
    float4 f = ((const float4*)kf)[i];
    ushort4 o;
    u32 b;
    b = __float_as_uint(f.x); o.x = (u16)((b + 0x7FFFu + ((b >> 16) & 1u)) >> 16);
    b = __float_as_uint(f.y); o.y = (u16)((b + 0x7FFFu + ((b >> 16) & 1u)) >> 16);
    b = __float_as_uint(f.z); o.z = (u16)((b + 0x7FFFu + ((b >> 16) & 1u)) >> 16);
    b = __float_as_uint(f.w); o.w = (u16)((b + 0x7FFFu + ((b >> 16) & 1u)) >> 16);
    ((ushort4*)kb)[i] = o;
}

// Bin edges into padded per-bucket regions with coalesced writes:
// rank via LDS int hist, scatter to LDS stage at block-local sorted position,
// then stream out (consecutive threads -> consecutive addresses within runs).
__global__ __launch_bounds__(BIN_TPB) void gc_bin(const int* __restrict__ rows,
                                                  const int* __restrict__ cols,
                                                  const float* __restrict__ values,
                                                  int* __restrict__ gcursor,
                                                  u64* __restrict__ edges, int nnz) {
    __shared__ u64 stage[BIN_TPB * BIN_EPT];   // 32 KB
    __shared__ int hist[NBUCK];
    __shared__ int lstart[NBUCK];
    __shared__ int delta[NBUCK];
    int t = threadIdx.x;
    if (t < NBUCK) hist[t] = 0;
    __syncthreads();

    int blockStart = blockIdx.x * (BIN_TPB * BIN_EPT);
    int cnt = min(BIN_TPB * BIN_EPT, nnz - blockStart);

    u64 rec[BIN_EPT];
    int bk[BIN_EPT];
    int rk[BIN_EPT];
#pragma unroll
    for (int k = 0; k < BIN_EPT; ++k) {
        int idx = blockStart + k * BIN_TPB + t;
        if (idx < nnz) {
            int r = rows[idx];
            u32 c = (u32)cols[idx];
            u32 v = __float_as_uint(values[idx]);
            int b = (int)(((u32)r * 512u) / 50000u);
            int lrow = r - rowbase_of((u32)b);
            rec[k] = ((u64)v << 32) | ((u64)(u32)b << 23) | ((u64)(u32)lrow << 16) | (u64)c;
            bk[k] = b;
            rk[k] = atomicAdd(&hist[b], 1);   // int LDS atomic: native ds_add
        } else {
            bk[k] = -1;
        }
    }
    __syncthreads();

    // exclusive scan of hist -> lstart; grab global cursor; delta = gbase - lstart
    int v0 = (t < NBUCK) ? hist[t] : 0;
    lstart[t] = v0;
    __syncthreads();
    for (int off = 1; off < NBUCK; off <<= 1) {
        int x = (t >= off) ? lstart[t - off] : 0;
        __syncthreads();
        lstart[t] += x;
        __syncthreads();
    }
    {
        int excl = lstart[t] - v0;
        int gbase = (v0 > 0) ? atomicAdd(&gcursor[t], v0) : 0;
        delta[t] = gbase - excl;
        lstart[t] = excl;
    }
    __syncthreads();

#pragma unroll
    for (int k = 0; k < BIN_EPT; ++k) {
        if (bk[k] >= 0) stage[lstart[bk[k]] + rk[k]] = rec[k];
    }
    __syncthreads();

    for (int i = t; i < cnt; i += BIN_TPB) {
        u64 r = stage[i];
        int b = (int)((r >> 23) & 0x1FF);
        int gpos = delta[b] + i;
        if (gpos < (b + 1) * CAP) edges[gpos] = r;   // overflow insurance
    }
}

// One block per bucket (512 blocks = 2/CU, 32 waves/CU). Phase 1: coalesced
// record load into REGISTERS + int-LDS-atomic rank. Phase 2: scan row hist.
// Phase 3: scatter records into LDS at row-sorted position. Phase 4: wave per
// row, lane per unit, register fma accumulation; fused bias+relu store.
__global__ __launch_bounds__(SPMM_TPB) void gc_spmm(const u64* __restrict__ edges,
                                                    const int* __restrict__ gcursor,
                                                    const u16* __restrict__ kb,
                                                    const float* __restrict__ bias,
                                                    float* __restrict__ out) {
    __shared__ u64 stage[CAP];        // 28.7 KB
    __shared__ int rhist[128];
    __shared__ int rstart[128];
    int b = blockIdx.x;
    int t = threadIdx.x;
    int rowlo = rowbase_of((u32)b);
    int nrows = rowbase_of((u32)b + 1u) - rowlo;   // 97 or 98
    int count = min(gcursor[b] - b * CAP, CAP);
    const u64* eb = edges + (size_t)b * CAP;

    if (t < 128) rhist[t] = 0;
    __syncthreads();

    // Phase 1: load + rank (records stay in registers)
    u64 rec[4];
    int rk[4], lr[4];
#pragma unroll
    for (int k = 0; k < 4; ++k) {
        int i = k * SPMM_TPB + t;
        if (i < count) {
            u64 r = eb[i];
            rec[k] = r;
            int l = (int)((r >> 16) & 0x7F);
            lr[k] = l;
            rk[k] = atomicAdd(&rhist[l], 1);
        } else {
            lr[k] = -1;
        }
    }
    __syncthreads();

    // Phase 2: exclusive scan of rhist[0..nrows) -> rstart (Hillis over 128)
    int v0 = (t < 128) ? rhist[t] : 0;
    if (t < 128) rstart[t] = v0;
    __syncthreads();
    for (int off = 1; off < 128; off <<= 1) {
        int x = 0;
        if (t < 128 && t >= off) x = rstart[t - off];
        __syncthreads();
        if (t < 128) rstart[t] += x;
        __syncthreads();
    }
    if (t < 128) rstart[t] -= v0;   // exclusive; rstart[nrows] == count
    __syncthreads();

    // Phase 3: scatter to row-sorted LDS positions
#pragma unroll
    for (int k = 0; k < 4; ++k) {
        if (lr[k] >= 0) stage[rstart[lr[k]] + rk[k]] = rec[k];
    }
    __syncthreads();

    // Phase 4: wave per row, lane per unit
    int lane = t & 63;
    int w = t >> 6;                  // 16 waves
    float bl = bias[lane];
    for (int row = w; row < nrows; row += 16) {
        int j = rstart[row];
        int e = rstart[row + 1];
        float acc = 0.0f;
        for (; j + 4 <= e; j += 4) {
            u64 r0 = stage[j + 0], r1 = stage[j + 1], r2 = stage[j + 2], r3 = stage[j + 3];
            float k0 = __uint_as_float((u32)kb[((u32)r0 & 0xFFFFu) * UNITS + lane] << 16);
            float k1 = __uint_as_float((u32)kb[((u32)r1 & 0xFFFFu) * UNITS + lane] << 16);
            float k2 = __uint_as_float((u32)kb[((u32)r2 & 0xFFFFu) * UNITS + lane] << 16);
            float k3 = __uint_as_float((u32)kb[((u32)r3 & 0xFFFFu) * UNITS + lane] << 16);
            acc = fmaf(__uint_as_float((u32)(r0 >> 32)), k0, acc);
            acc = fmaf(__uint_as_float((u32)(r1 >> 32)), k1, acc);
            acc = fmaf(__uint_as_float((u32)(r2 >> 32)), k2, acc);
            acc = fmaf(__uint_as_float((u32)(r3 >> 32)), k3, acc);
        }
        for (; j < e; ++j) {
            u64 r = stage[j];
            float k = __uint_as_float((u32)kb[((u32)r & 0xFFFFu) * UNITS + lane] << 16);
            acc = fmaf(__uint_as_float((u32)(r >> 32)), k, acc);
        }
        out[(size_t)(rowlo + row) * UNITS + lane] = fmaxf(acc + bl, 0.0f);
    }
}

extern "C" void kernel_launch(void* const* d_in, const int* in_sizes, int n_in,
                              void* d_out, int out_size, void* d_ws, size_t ws_size,
                              hipStream_t stream) {
    const int*   rows   = (const int*)d_in[0];
    const int*   cols   = (const int*)d_in[1];
    const float* values = (const float*)d_in[2];
    const float* kern   = (const float*)d_in[3];
    const float* bias   = (const float*)d_in[4];
    float* out = (float*)d_out;

    const int nnz = in_sizes[0];

    char* ws = (char*)d_ws;
    u16* kb      = (u16*)(ws + 0);
    int* gcursor = (int*)(ws + 6400000);
    u64* edges   = (u64*)(ws + 6402048);

    int n4 = (NNODES * UNITS) / 4;  // 800000
    gc_prep<<<(n4 + 255) / 256, 256, 0, stream>>>(kern, kb, gcursor, n4);

    gc_bin<<<(nnz + BIN_TPB * BIN_EPT - 1) / (BIN_TPB * BIN_EPT), BIN_TPB, 0, stream>>>(
        rows, cols, values, gcursor, edges, nnz);

    gc_spmm<<<NBUCK, SPMM_TPB, 0, stream>>>(edges, gcursor, kb, bias, out);
}